// Round 11
// baseline (285.548 us; speedup 1.0000x reference)
//
#include <hip/hip_runtime.h>

// ============================================================================
// Attention_14362370637857 on MI355X (gfx950).
// B=2, S=2048, D_MODEL=2048, NH=32, NKV=8 (GQA rep=4), DH=64.
//
// v17: GEMMs shrunk to 128x128 / BK=64 / 4 waves / 64 KB LDS -> 2 blocks/CU
// co-resident (m97-class config; cross-block TLP hides tile-top vmcnt waits,
// which R8 counters showed to be the binding constraint at 1 block/CU).
// Same free-flow 2-barrier tile + depth-2 counted-vmcnt ledger + XOR-8
// swizzle. attn v16 (67 us, split counted waits) unchanged.
// ============================================================================

typedef __attribute__((ext_vector_type(8))) short short8;   // 8 bf16
typedef __attribute__((ext_vector_type(4))) short short4v;  // 4 bf16 = 8B
typedef __attribute__((ext_vector_type(4))) float f32x4;    // MFMA 16x16 C/D

__device__ __forceinline__ short f2bs(float f) {  // f32 -> bf16 bits, RNE
  unsigned u = __float_as_uint(f);
  u = (u + 0x7fffu + ((u >> 16) & 1u)) >> 16;
  return (short)u;
}
__device__ __forceinline__ float bs2f(short s) {  // bf16 bits -> f32
  return __uint_as_float(((unsigned)(unsigned short)s) << 16);
}

__device__ __forceinline__ void async_ld16(const void* g, void* l) {
  __builtin_amdgcn_global_load_lds((__attribute__((address_space(1))) void*)(g),
                                   (__attribute__((address_space(3))) void*)(l),
                                   16, 0, 0);
}

#define BARRIER()                       \
  do {                                  \
    asm volatile("" ::: "memory");      \
    __builtin_amdgcn_s_barrier();       \
    asm volatile("" ::: "memory");      \
  } while (0)
#define LGKM0()                                          \
  do {                                                   \
    asm volatile("s_waitcnt lgkmcnt(0)" ::: "memory");   \
    __builtin_amdgcn_sched_barrier(0);                   \
  } while (0)
#define VMCNT(n) asm volatile("s_waitcnt vmcnt(" #n ")" ::: "memory")
#define MFMA16(a, b, c) \
  (c) = __builtin_amdgcn_mfma_f32_16x16x32_bf16((a), (b), (c), 0, 0, 0)

// Pack 4 f32 -> 4 bf16 (RNE) via v_cvt_pk_bf16_f32 (no builtin on gfx950).
__device__ __forceinline__ short4v pk4bf16(float p0, float p1, float p2,
                                           float p3) {
  union {
    unsigned u[2];
    short4v s;
  } pk;
  asm("v_cvt_pk_bf16_f32 %0, %1, %2" : "=v"(pk.u[0]) : "v"(p0), "v"(p1));
  asm("v_cvt_pk_bf16_f32 %0, %1, %2" : "=v"(pk.u[1]) : "v"(p2), "v"(p3));
  return pk.s;
}

// ----------------------------------------------------------------------------
// Block-uniform dtype sniff: read the first 512 shorts of residual as bf16;
// if input is really f32, mantissa-half shorts decode to huge bf16 values.
// ----------------------------------------------------------------------------
__device__ __forceinline__ int block_sniff_f32(const short* __restrict__ r,
                                               int* bad) {
  if (threadIdx.x == 0) *bad = 0;
  __syncthreads();
  int my = 0;
  for (int i = threadIdx.x; i < 512; i += blockDim.x) {
    float x = bs2f(r[i]);
    if (!(fabsf(x) < 100.0f)) my = 1;
  }
  if (my) atomicOr(bad, 1);
  __syncthreads();
  return *bad;
}

// ----------------------------------------------------------------------------
// prep: blocks [0,7168) convert residual/W_Q/W_K/W_V -> canonical bf16;
//       blocks [7168,8192) transpose W_O -> W_O^T (flag-aware read).
// ----------------------------------------------------------------------------
__global__ __launch_bounds__(256) void prep_kernel(
    const void* __restrict__ s0, const void* __restrict__ s1,
    const void* __restrict__ s2, const void* __restrict__ s3,
    short* __restrict__ d0, short* __restrict__ d1, short* __restrict__ d2,
    short* __restrict__ d3, const void* __restrict__ wo,
    short* __restrict__ wot) {
  __shared__ short tile[64][65];
  __shared__ int badsh;
  const int isf = block_sniff_f32((const short*)s0, &badsh);
  const int bid = blockIdx.x;
  if (bid < 7168) {
    long off = (long)bid * 256 + threadIdx.x;
    const void* src;
    short* dst;
    if (off < 1048576) {
      src = s0; dst = d0;
    } else if ((off -= 1048576) < 524288) {
      src = s1; dst = d1;
    } else if ((off -= 524288) < 131072) {
      src = s2; dst = d2;
    } else {
      off -= 131072; src = s3; dst = d3;
    }
    const long e = off * 8;
    short8 v;
    if (isf) {
      const float* f = (const float*)src + e;
      const f32x4 a = *(const f32x4*)(f);
      const f32x4 b = *(const f32x4*)(f + 4);
#pragma unroll
      for (int j = 0; j < 4; ++j) {
        v[j] = f2bs(a[j]);
        v[4 + j] = f2bs(b[j]);
      }
    } else {
      v = *(const short8*)((const short*)src + e);
    }
    *(short8*)(dst + e) = v;
  } else {
    const int tb = bid - 7168;
    const int bx = tb & 31, by = tb >> 5;
    const int tx = threadIdx.x & 63, ty = threadIdx.x >> 6;
#pragma unroll
    for (int i = 0; i < 16; ++i) {
      const int r = ty + i * 4;
      const size_t idx = (size_t)(by * 64 + r) * 2048 + bx * 64 + tx;
      tile[r][tx] =
          isf ? f2bs(((const float*)wo)[idx]) : ((const short*)wo)[idx];
    }
    __syncthreads();
#pragma unroll
    for (int i = 0; i < 16; ++i) {
      const int r = ty + i * 4;
      wot[(size_t)(bx * 64 + r) * 2048 + by * 64 + tx] = tile[tx][r];
    }
  }
}

// ----------------------------------------------------------------------------
// gemm128 v17: C = cscale*A[M,K]*B[N,K]^T, 128x128 tile, BK=64, 4 waves
// (2M x 2N, per-wave 64x64 out). LDS 64 KB -> 2 blocks/CU co-resident.
// Free-flow 2-barrier tile; depth-2 ledger: prologue stages tiles 0 and 1
// (16 loads); at tile t's mid barrier (Ac/Bc read-dead) stage A/B(t+2) (8
// loads). Tile-top vmcnt(8) waits A/B(t) (issued >= 1 full tile earlier),
// leaving t+1's 8 in flight; vmcnt(0) entering the last tile.
// XOR-8 chunk swizzle (128B rows, unchanged from the verified pattern).
// ----------------------------------------------------------------------------
__device__ __forceinline__ void gemm128(const short* __restrict__ A, int lda,
                                        const short* __restrict__ B, int ldb,
                                        void* __restrict__ C, int ldc,
                                        int rowBase, int colBase, int K,
                                        short* SM, int outF32, float cscale) {
  const int t = threadIdx.x;
  const int wave = t >> 6;
  const int lane = t & 63;
  const int quad = lane >> 4;
  const int m16 = lane & 15;
  const int wr = (wave >> 1) * 64;  // 2 M-waves
  const int wc = (wave & 1) * 64;   // 2 N-waves

  short* const As0 = SM;            // 16 KB each: 128 rows x 64 bf16
  short* const As1 = SM + 8192;
  short* const Bs0 = SM + 16384;
  short* const Bs1 = SM + 24576;    // total 64 KB

  const int sr = t >> 3;  // 0..31
  const int sc8 = ((t & 7) ^ (sr & 7)) * 8;
  const short* aS = A + (size_t)(rowBase + sr) * lda + sc8;
  const short* bS = B + (size_t)(colBase + sr) * ldb + sc8;
  const int dOff = wave * 512;  // wave w writes rows w*8..w*8+7 of a group

#define STG_A(buf, rg, kt) \
  async_ld16(aS + (size_t)(rg) * lda + (kt) * 64, (buf) + (rg) * 64 + dOff)
#define STG_B(buf, rg, kt) \
  async_ld16(bS + (size_t)(rg) * ldb + (kt) * 64, (buf) + (rg) * 64 + dOff)
#define RD(buf, row0, kh)                          \
  (*(const short8*)((buf) + ((row0) + m16) * 64 +  \
                    ((((kh) * 4 + quad) ^ (m16 & 7)) * 8)))

  const int nT = K >> 6;
  // prologue: tiles 0 and 1 fully staged -> 16 loads in flight.
  STG_A(As0, 0, 0); STG_A(As0, 32, 0); STG_A(As0, 64, 0); STG_A(As0, 96, 0);
  STG_B(Bs0, 0, 0); STG_B(Bs0, 32, 0); STG_B(Bs0, 64, 0); STG_B(Bs0, 96, 0);
  if (nT > 1) {
    STG_A(As1, 0, 1); STG_A(As1, 32, 1); STG_A(As1, 64, 1); STG_A(As1, 96, 1);
    STG_B(Bs1, 0, 1); STG_B(Bs1, 32, 1); STG_B(Bs1, 64, 1); STG_B(Bs1, 96, 1);
  }

  f32x4 acc[4][4] = {};
  for (int tt = 0; tt < nT; ++tt) {
    short* const Ac = (tt & 1) ? As1 : As0;  // tile tt's A; dest for A(tt+2)
    short* const Bc = (tt & 1) ? Bs1 : Bs0;  // tile tt's B; dest for B(tt+2)

    // ---- tile-top: A/B(tt) are the 8 oldest outstanding loads ----
    if (tt + 1 < nT) {
      VMCNT(8);  // leave A/B(tt+1) in flight
    } else {
      VMCNT(0);
    }
    BARRIER();

    // ---- kh=0 half (reads free-flow with MFMAs) ----
    short8 a0[4], b0[4];
#pragma unroll
    for (int i = 0; i < 4; ++i) a0[i] = RD(Ac, wr + i * 16, 0);
#pragma unroll
    for (int j = 0; j < 4; ++j) b0[j] = RD(Bc, wc + j * 16, 0);
#pragma unroll
    for (int i = 0; i < 4; ++i)
#pragma unroll
      for (int j = 0; j < 4; ++j) MFMA16(a0[i], b0[j], acc[i][j]);

    // ---- kh=1 reads (hidden under kh=0 MFMAs) ----
    short8 a1[4], b1[4];
#pragma unroll
    for (int i = 0; i < 4; ++i) a1[i] = RD(Ac, wr + i * 16, 1);
#pragma unroll
    for (int j = 0; j < 4; ++j) b1[j] = RD(Bc, wc + j * 16, 1);
    LGKM0();
    BARRIER();  // all waves done reading Ac/Bc -> safe to overwrite

    // ---- stage tile tt+2 (A and B) into the freed buffers ----
    if (tt + 2 < nT) {
      STG_A(Ac, 0, tt + 2); STG_A(Ac, 32, tt + 2);
      STG_A(Ac, 64, tt + 2); STG_A(Ac, 96, tt + 2);
      STG_B(Bc, 0, tt + 2); STG_B(Bc, 32, tt + 2);
      STG_B(Bc, 64, tt + 2); STG_B(Bc, 96, tt + 2);
    }

#pragma unroll
    for (int i = 0; i < 4; ++i)
#pragma unroll
      for (int j = 0; j < 4; ++j) MFMA16(a1[i], b1[j], acc[i][j]);
  }

  // ---- epilogue: per-wave f32 LDS transit (16 KB/wave = 64 KB total) ----
  // Safe: vmcnt(0) at last tile top + last mid barrier drained all reads.
  float* const F = (float*)SM + wave * 4096;
#pragma unroll
  for (int i = 0; i < 4; ++i)
#pragma unroll
    for (int j = 0; j < 4; ++j)
#pragma unroll
      for (int r = 0; r < 4; ++r)
        F[(i * 16 + quad * 4 + r) * 64 + j * 16 + m16] =
            acc[i][j][r] * cscale;
  LGKM0();
#pragma unroll
  for (int p = 0; p < 16; ++p) {
    const int row = p * 4 + quad;
    const f32x4 vv = *(const f32x4*)(F + row * 64 + m16 * 4);
    const size_t gi =
        (size_t)(rowBase + wr + row) * ldc + colBase + wc + m16 * 4;
    if (outF32) {
      *(f32x4*)((float*)C + gi) = vv;
    } else {
      short4v s;
#pragma unroll
      for (int r = 0; r < 4; ++r) s[r] = f2bs(vv[r]);
      *(short4v*)((short*)C + gi) = s;
    }
  }
#undef STG_A
#undef STG_B
#undef RD
}

// grid: 768 blocks (32 row-tiles x 24 col-tiles of 128: Q 16, K 4, V 4),
// 256 threads, 64 KB LDS -> 2 blocks/CU. Q pre-scaled by 1/sqrt(64)*log2e.
__global__ __launch_bounds__(256) void qkv_gemm_kernel(
    const short* __restrict__ R, const short* __restrict__ WQ,
    const short* __restrict__ WK, const short* __restrict__ WV,
    short* __restrict__ q, short* __restrict__ k, short* __restrict__ v) {
  __shared__ __align__(16) short SM[32768];  // 64 KB
  const int lid = blockIdx.x;
  const int nl = (lid & 7) * 96 + (lid >> 3);  // XCD-bijective (768%8==0)
  const int ct = nl % 24;
  const int rt = nl / 24;
  const short* Bm;
  short* Cout;
  int colBase, ldc;
  float cs = 1.0f;
  if (ct < 16) {
    Bm = WQ; Cout = q; colBase = ct * 128; ldc = 2048;
    cs = 0.125f * 1.44269504088896340736f;
  } else if (ct < 20) {
    Bm = WK; Cout = k; colBase = (ct - 16) * 128; ldc = 512;
  } else {
    Bm = WV; Cout = v; colBase = (ct - 20) * 128; ldc = 512;
  }
  gemm128(R, 2048, Bm, 2048, Cout, ldc, rt * 128, colBase, 2048, SM, 0, cs);
}

// grid: 512 blocks (32 row-tiles x 16 col-tiles of 128), 256 threads.
__global__ __launch_bounds__(256) void out_gemm_kernel(
    const short* __restrict__ A, const short* __restrict__ Bt,
    void* __restrict__ C, const short* __restrict__ sniffsrc) {
  __shared__ __align__(16) short SM[32768];  // 64 KB
  const int outF32 = block_sniff_f32(sniffsrc, (int*)SM);
  const int lid = blockIdx.x;
  const int nl = (lid & 7) * 64 + (lid >> 3);  // XCD-bijective (512%8==0)
  const int ct = nl & 15;
  const int rt = nl >> 4;
  gemm128(A, 2048, Bt, 2048, C, 2048, rt * 128, ct * 128, 2048, SM, outF32,
          1.0f);
}

// ----------------------------------------------------------------------------
// v [2,2048,512] -> vT [2,512,2048]
// ----------------------------------------------------------------------------
__global__ __launch_bounds__(256) void vt_kernel(const short* __restrict__ v,
                                                 short* __restrict__ vt) {
  __shared__ short tile[64][65];
  const int hb = blockIdx.x * 64, pb = blockIdx.y * 64, b = blockIdx.z;
  const int tx = threadIdx.x & 63, ty = threadIdx.x >> 6;
#pragma unroll
  for (int i = 0; i < 16; ++i) {
    const int r = ty + i * 4;
    tile[r][tx] = v[((size_t)(b * 2048 + pb + r)) * 512 + hb + tx];
  }
  __syncthreads();
#pragma unroll
  for (int i = 0; i < 16; ++i) {
    const int r = ty + i * 4;
    vt[((size_t)(b * 512 + hb + r)) * 2048 + pb + tx] = tile[tx][r];
  }
}

// ----------------------------------------------------------------------------
// Causal flash attention v16 (unchanged, 67 us): split counted waits.
//   top: vmcnt(2) waits K(t) only; barrier; issue K(t+1).
//   mid: vmcnt(2|0) waits V(t); barrier; issue V(t+1).
// Raw s_barrier everywhere -- no implicit full drain.
// ----------------------------------------------------------------------------
__global__ __launch_bounds__(256, 3) void attn_kernel(
    const short* __restrict__ qbuf, const short* __restrict__ kbuf,
    const short* __restrict__ vtb, short* __restrict__ obuf) {
  __shared__ __align__(16) short Ks[2][64 * 64];  // 16 KB K double-buffer
  __shared__ __align__(16) short Vs[2][64 * 64];  // 16 KB V^T double-buffer
  __shared__ __align__(16) short Pb[4][32 * 64];  // 16 KB per-wave P transit

  const int b = blockIdx.x >> 3;
  const int kv = blockIdx.x & 7;
  const int qc = 63 - blockIdx.y;  // long-first dispatch
  const int t = threadIdx.x;
  const int wave = t >> 6;
  const int hd = kv * 4 + wave;
  const int lane = t & 63;
  const int quad = lane >> 4;
  const int col = lane & 15;
  const int rb0 = qc * 32;

  // Q B-frags: B[k=quad*8+j (+32*kh)][n=col] = Q[qrow][h] (pre-scaled)
  short8 qf[2][2];
#pragma unroll
  for (int nt = 0; nt < 2; ++nt) {
    const int qr = rb0 + nt * 16 + col;
    const short* qp = qbuf + ((size_t)(b * 2048 + qr)) * 2048 + hd * 64 + quad * 8;
    qf[nt][0] = *(const short8*)(qp);
    qf[nt][1] = *(const short8*)(qp + 32);
  }

  // all-ones bf16 A-frag for MFMA row-sum
  short8 ones;
#pragma unroll
  for (int i = 0; i < 8; ++i) ones[i] = (short)0x3F80;

  f32x4 oacc[2][4] = {};
  f32x4 sacc[2] = {};  // row-sum accumulators (all regs identical)

  short* P = &Pb[wave][0];
  const int swz = 4 * (col & 3);  // P chunk swizzle

  const int sRow = t >> 3;
  const int sPos = t & 7;
  const int r1 = sRow + 32;
  const short* kRow0 = kbuf + ((size_t)(b * 2048 + sRow)) * 512 + kv * 64 +
                       ((sPos ^ (sRow & 7)) * 8);
  const short* kRow1 = kbuf + ((size_t)(b * 2048 + r1)) * 512 + kv * 64 +
                       ((sPos ^ (r1 & 7)) * 8);
  const short* vRow0 = vtb + ((size_t)(b * 512 + kv * 64 + sRow)) * 2048 +
                       ((sPos ^ (sRow & 7)) * 8);
  const short* vRow1 = vtb + ((size_t)(b * 512 + kv * 64 + r1)) * 2048 +
                       ((sPos ^ (r1 & 7)) * 8);

  const int nkt = (qc >> 1) + 1;  // exact causal trip count (same all waves)

  // prologue: stage K tile 0 FIRST, then V tile 0 (issue order = wait order)
  async_ld16(kRow0, &Ks[0][wave * 512]);
  async_ld16(kRow1, &Ks[0][2048 + wave * 512]);
  async_ld16(vRow0, &Vs[0][wave * 512]);
  async_ld16(vRow1, &Vs[0][2048 + wave * 512]);

  for (int kt = 0; kt < nkt; ++kt) {
    const int nb = (kt + 1) & 1;
    // ---- top: K(kt) resident; V(kt) still in flight ----
    VMCNT(2);
    BARRIER();  // all waves' K(kt) in LDS; K[nb] readers done (prev mid bar)
    if (kt + 1 < nkt) {
      const size_t ko = (size_t)(kt + 1) * 64 * 512;  // K: 64 rows ahead
      async_ld16(kRow0 + ko, &Ks[nb][wave * 512]);
      async_ld16(kRow1 + ko, &Ks[nb][2048 + wave * 512]);
    }
    const int ktb = kt * 64;
    const short* ks = &Ks[kt & 1][0];
    const short* vs = &Vs[kt & 1][0];

    // ---- K A-frags from LDS: A[m=mt*16+col][k=quad*8+j (+32kh)]
    short8 kf[4][2];
#pragma unroll
    for (int mt = 0; mt < 4; ++mt) {
      const int krow = mt * 16 + col;  // krow&7 == col&7
      kf[mt][0] = *(const short8*)(ks + krow * 64 + ((quad ^ (col & 7)) * 8));
      kf[mt][1] = *(const short8*)(ks + krow * 64 + (((4 + quad) ^ (col & 7)) * 8));
    }

#pragma unroll
    for (int nt = 0; nt < 2; ++nt) {
      const int rb = rb0 + nt * 16;

      f32x4 st[4];
#pragma unroll
      for (int mt = 0; mt < 4; ++mt) {
        f32x4 z = {0.f, 0.f, 0.f, 0.f};
        z = __builtin_amdgcn_mfma_f32_16x16x32_bf16(kf[mt][0], qf[nt][0], z, 0, 0, 0);
        z = __builtin_amdgcn_mfma_f32_16x16x32_bf16(kf[mt][1], qf[nt][1], z, 0, 0, 0);
        st[mt] = z;
      }

      if (ktb + 63 > rb) {  // diagonal overlap: per-score causal mask
        const int qrow = rb + col;
#pragma unroll
        for (int mt = 0; mt < 4; ++mt)
#pragma unroll
          for (int r = 0; r < 4; ++r)
            if (ktb + mt * 16 + quad * 4 + r > qrow) st[mt][r] = -1.0e30f;
      }

      // ---- one-pass softmax: P = exp2(S); masked -> 0; sum via MFMA later
#pragma unroll
      for (int mt = 0; mt < 4; ++mt) {
        const float p0 = exp2f(st[mt][0]);
        const float p1 = exp2f(st[mt][1]);
        const float p2 = exp2f(st[mt][2]);
        const float p3 = exp2f(st[mt][3]);
        *(short4v*)(P + (nt * 16 + col) * 64 + (quad + 4 * (mt ^ (col & 3))) * 4) =
            pk4bf16(p0, p1, p2, p3);
      }
    }

    LGKM0();  // P visible wave-wide (P is per-wave)

    // ---- mid: V(kt) resident; K(kt+1) stays in flight under PV ----
    if (kt + 1 < nkt) {
      VMCNT(2);
    } else {
      VMCNT(0);  // no K(kt+1) issued -> V(kt) is all that's outstanding
    }
    BARRIER();  // all waves' V(kt) in LDS; V[nb] readers done (prev top bar)
    if (kt + 1 < nkt) {
      const int vo = (kt + 1) * 64;  // V^T: 64 keys ahead
      async_ld16(vRow0 + vo, &Vs[nb][wave * 512]);
      async_ld16(vRow1 + vo, &Vs[nb][2048 + wave * 512]);
    }

    // P^T B-frags: B[k=key=quad*8+j (+32kh)][n=col]
    short8 pf[2][2];
#pragma unroll
    for (int nt = 0; nt < 2; ++nt) {
      const int base = (nt * 16 + col) * 64;
      pf[nt][0] = *(const short8*)(P + base + ((2 * quad) ^ swz) * 4);
      pf[nt][1] = *(const short8*)(P + base + ((8 + 2 * quad) ^ swz) * 4);
    }

    // ---- row-sum via ones-row MFMA: D[*][q] = sum_k P[k][q]
#pragma unroll
    for (int nt = 0; nt < 2; ++nt) {
      sacc[nt] = __builtin_amdgcn_mfma_f32_16x16x32_bf16(ones, pf[nt][0],
                                                         sacc[nt], 0, 0, 0);
      sacc[nt] = __builtin_amdgcn_mfma_f32_16x16x32_bf16(ones, pf[nt][1],
                                                         sacc[nt], 0, 0, 0);
    }

    // ---- V^T A-frags from LDS + PV accumulate
#pragma unroll
    for (int ct = 0; ct < 4; ++ct) {
      const int h = ct * 16 + col;  // h&7 == col&7
      const short8 va = *(const short8*)(vs + h * 64 + ((quad ^ (col & 7)) * 8));
      const short8 vb = *(const short8*)(vs + h * 64 + (((4 + quad) ^ (col & 7)) * 8));
#pragma unroll
      for (int nt = 0; nt < 2; ++nt) {
        oacc[nt][ct] = __builtin_amdgcn_mfma_f32_16x16x32_bf16(
            va, pf[nt][0], oacc[nt][ct], 0, 0, 0);
        oacc[nt][ct] = __builtin_amdgcn_mfma_f32_16x16x32_bf16(
            vb, pf[nt][1], oacc[nt][ct], 0, 0, 0);
      }
    }
  }

  // ---- epilogue: O/l -> LDS (rows qlocal x 64 h) -> line-coalesced stores
  const float inv0 = 1.0f / sacc[0][0];
  const float inv1 = 1.0f / sacc[1][0];
#pragma unroll
  for (int nt = 0; nt < 2; ++nt) {
    const float inv = nt ? inv1 : inv0;
#pragma unroll
    for (int ct = 0; ct < 4; ++ct) {
      *(short4v*)(P + (nt * 16 + col) * 64 + ct * 16 + quad * 4) =
          pk4bf16(oacc[nt][ct][0] * inv, oacc[nt][ct][1] * inv,
                  oacc[nt][ct][2] * inv, oacc[nt][ct][3] * inv);
    }
  }
  asm volatile("s_waitcnt lgkmcnt(0)" ::: "memory");
  // 8 lanes x 16B cover one 128B output row; 64 lanes -> 8 rows per pass.
#pragma unroll
  for (int p = 0; p < 4; ++p) {
    const int qlocal = (lane >> 3) + 8 * p;
    const short8 row = *(const short8*)(P + qlocal * 64 + (lane & 7) * 8);
    *(short8*)(obuf + ((size_t)(b * 2048 + rb0 + qlocal)) * 2048 + hd * 64 +
               (lane & 7) * 8) = row;
  }
}

// ----------------------------------------------------------------------------
extern "C" void kernel_launch(void* const* d_in, const int* in_sizes, int n_in,
                              void* d_out, int out_size, void* d_ws,
                              size_t ws_size, hipStream_t stream) {
  char* ws = (char*)d_ws;
  short* rbuf = (short*)(ws + 256);  // [4096,2048] bf16
  short* wqb = rbuf + 8388608;       // [2048,2048]
  short* wkb = wqb + 4194304;        // [512,2048]
  short* wvb = wkb + 1048576;        // [512,2048]
  short* kbuf = wvb + 1048576;       // [4096,512]
  short* vbuf = kbuf + 2097152;      // [4096,512]
  short* abuf = vbuf + 2097152;      // [4096,2048]
  short* wot = abuf + 8388608;       // [2048,2048]
  short* vtb = wqb;                  // [2,512,2048] aliases spent W_Q copy
  short* qbuf = (short*)d_out;       // q scratch lives in d_out

  hipLaunchKernelGGL(prep_kernel, dim3(8192), dim3(256), 0, stream,
                     d_in[0], d_in[1], d_in[2], d_in[3], rbuf, wqb, wkb, wvb,
                     d_in[4], wot);
  hipLaunchKernelGGL(qkv_gemm_kernel, dim3(768), dim3(256), 0, stream,
                     rbuf, wqb, wkb, wvb, qbuf, kbuf, vbuf);
  hipLaunchKernelGGL(vt_kernel, dim3(8, 32, 2), dim3(256), 0, stream,
                     vbuf, vtb);
  hipLaunchKernelGGL(attn_kernel, dim3(16, 64), dim3(256), 0, stream,
                     qbuf, kbuf, vtb, abuf);
  hipLaunchKernelGGL(out_gemm_kernel, dim3(512), dim3(256), 0, stream,
                     abuf, wot, (void*)d_out, (const short*)d_in[0]);
}

// Round 12
// 264.720 us; speedup vs baseline: 1.0787x; 1.0787x over previous
//
#include <hip/hip_runtime.h>

// ============================================================================
// Attention_14362370637857 on MI355X (gfx950).
// B=2, S=2048, D_MODEL=2048, NH=32, NKV=8 (GQA rep=4), DH=64.
//
// v18: best-known component assembly.
//  - qkv = gemm256 (256^2, 192 blocks, v12 free-flow 2-barrier ledger:
//    B(t+1)@top, A(t+2)@mid, vmcnt(4)) -- R7-verified.
//  - out = gemm256x128 (256x128, 256 blocks, v12 ledger) -- R7-verified.
//    (The depth-2 "stage-at-mid vmcnt(6/8)" ledger of R9-R11 regressed out_gemm
//    ~16 us; reverted.)
//  - attn = v16 split counted waits (67.0 us, R10-verified).
//  - prep/vt unchanged.
// ============================================================================

typedef __attribute__((ext_vector_type(8))) short short8;   // 8 bf16
typedef __attribute__((ext_vector_type(4))) short short4v;  // 4 bf16 = 8B
typedef __attribute__((ext_vector_type(4))) float f32x4;    // MFMA 16x16 C/D

__device__ __forceinline__ short f2bs(float f) {  // f32 -> bf16 bits, RNE
  unsigned u = __float_as_uint(f);
  u = (u + 0x7fffu + ((u >> 16) & 1u)) >> 16;
  return (short)u;
}
__device__ __forceinline__ float bs2f(short s) {  // bf16 bits -> f32
  return __uint_as_float(((unsigned)(unsigned short)s) << 16);
}

__device__ __forceinline__ void async_ld16(const void* g, void* l) {
  __builtin_amdgcn_global_load_lds((__attribute__((address_space(1))) void*)(g),
                                   (__attribute__((address_space(3))) void*)(l),
                                   16, 0, 0);
}

#define BARRIER()                       \
  do {                                  \
    asm volatile("" ::: "memory");      \
    __builtin_amdgcn_s_barrier();       \
    asm volatile("" ::: "memory");      \
  } while (0)
#define LGKM0()                                          \
  do {                                                   \
    asm volatile("s_waitcnt lgkmcnt(0)" ::: "memory");   \
    __builtin_amdgcn_sched_barrier(0);                   \
  } while (0)
#define VMCNT(n) asm volatile("s_waitcnt vmcnt(" #n ")" ::: "memory")
#define MFMA16(a, b, c) \
  (c) = __builtin_amdgcn_mfma_f32_16x16x32_bf16((a), (b), (c), 0, 0, 0)

// Pack 4 f32 -> 4 bf16 (RNE) via v_cvt_pk_bf16_f32 (no builtin on gfx950).
__device__ __forceinline__ short4v pk4bf16(float p0, float p1, float p2,
                                           float p3) {
  union {
    unsigned u[2];
    short4v s;
  } pk;
  asm("v_cvt_pk_bf16_f32 %0, %1, %2" : "=v"(pk.u[0]) : "v"(p0), "v"(p1));
  asm("v_cvt_pk_bf16_f32 %0, %1, %2" : "=v"(pk.u[1]) : "v"(p2), "v"(p3));
  return pk.s;
}

// ----------------------------------------------------------------------------
// Block-uniform dtype sniff: read the first 512 shorts of residual as bf16;
// if input is really f32, mantissa-half shorts decode to huge bf16 values.
// ----------------------------------------------------------------------------
__device__ __forceinline__ int block_sniff_f32(const short* __restrict__ r,
                                               int* bad) {
  if (threadIdx.x == 0) *bad = 0;
  __syncthreads();
  int my = 0;
  for (int i = threadIdx.x; i < 512; i += blockDim.x) {
    float x = bs2f(r[i]);
    if (!(fabsf(x) < 100.0f)) my = 1;
  }
  if (my) atomicOr(bad, 1);
  __syncthreads();
  return *bad;
}

// ----------------------------------------------------------------------------
// prep: blocks [0,7168) convert residual/W_Q/W_K/W_V -> canonical bf16;
//       blocks [7168,8192) transpose W_O -> W_O^T (flag-aware read).
// ----------------------------------------------------------------------------
__global__ __launch_bounds__(256) void prep_kernel(
    const void* __restrict__ s0, const void* __restrict__ s1,
    const void* __restrict__ s2, const void* __restrict__ s3,
    short* __restrict__ d0, short* __restrict__ d1, short* __restrict__ d2,
    short* __restrict__ d3, const void* __restrict__ wo,
    short* __restrict__ wot) {
  __shared__ short tile[64][65];
  __shared__ int badsh;
  const int isf = block_sniff_f32((const short*)s0, &badsh);
  const int bid = blockIdx.x;
  if (bid < 7168) {
    long off = (long)bid * 256 + threadIdx.x;
    const void* src;
    short* dst;
    if (off < 1048576) {
      src = s0; dst = d0;
    } else if ((off -= 1048576) < 524288) {
      src = s1; dst = d1;
    } else if ((off -= 524288) < 131072) {
      src = s2; dst = d2;
    } else {
      off -= 131072; src = s3; dst = d3;
    }
    const long e = off * 8;
    short8 v;
    if (isf) {
      const float* f = (const float*)src + e;
      const f32x4 a = *(const f32x4*)(f);
      const f32x4 b = *(const f32x4*)(f + 4);
#pragma unroll
      for (int j = 0; j < 4; ++j) {
        v[j] = f2bs(a[j]);
        v[4 + j] = f2bs(b[j]);
      }
    } else {
      v = *(const short8*)((const short*)src + e);
    }
    *(short8*)(dst + e) = v;
  } else {
    const int tb = bid - 7168;
    const int bx = tb & 31, by = tb >> 5;
    const int tx = threadIdx.x & 63, ty = threadIdx.x >> 6;
#pragma unroll
    for (int i = 0; i < 16; ++i) {
      const int r = ty + i * 4;
      const size_t idx = (size_t)(by * 64 + r) * 2048 + bx * 64 + tx;
      tile[r][tx] =
          isf ? f2bs(((const float*)wo)[idx]) : ((const short*)wo)[idx];
    }
    __syncthreads();
#pragma unroll
    for (int i = 0; i < 16; ++i) {
      const int r = ty + i * 4;
      wot[(size_t)(bx * 64 + r) * 2048 + by * 64 + tx] = tile[tx][r];
    }
  }
}

// ----------------------------------------------------------------------------
// gemm256 (R7-verified): C = cscale*A*B^T, 256x256, BK=64, 8 waves (2Mx4N),
// free-flow 2-barrier tile, v12 ledger: B(t+1)@top, A(t+2)@mid, vmcnt(4).
// ----------------------------------------------------------------------------
__device__ __forceinline__ void gemm256(const short* __restrict__ A, int lda,
                                        const short* __restrict__ B, int ldb,
                                        void* __restrict__ C, int ldc,
                                        int rowBase, int colBase, int K,
                                        short* SM, int outF32, float cscale) {
  const int t = threadIdx.x;
  const int wave = t >> 6;
  const int lane = t & 63;
  const int quad = lane >> 4;
  const int m16 = lane & 15;
  const int wr = (wave >> 2) * 128;  // 2 M-waves
  const int wc = (wave & 3) * 64;    // 4 N-waves

  short* const As0 = SM;             // 32 KB each buffer: 256 rows x 64 bf16
  short* const As1 = SM + 16384;
  short* const Bs0 = SM + 32768;
  short* const Bs1 = SM + 49152;

  const int sr = t >> 3;  // 0..63
  const int sc8 = ((t & 7) ^ (sr & 7)) * 8;
  const short* aS = A + (size_t)(rowBase + sr) * lda + sc8;
  const short* bS = B + (size_t)(colBase + sr) * ldb + sc8;
  const int dOff = wave * 512;

#define STG_A(buf, rg, kt) \
  async_ld16(aS + (size_t)(rg) * lda + (kt) * 64, (buf) + (rg) * 64 + dOff)
#define STG_B(buf, rg, kt) \
  async_ld16(bS + (size_t)(rg) * ldb + (kt) * 64, (buf) + (rg) * 64 + dOff)
#define RD(buf, row0, kh)                          \
  (*(const short8*)((buf) + ((row0) + m16) * 64 +  \
                    ((((kh) * 4 + quad) ^ (m16 & 7)) * 8)))

  const int nT = K >> 6;
  STG_A(As0, 0, 0); STG_A(As0, 64, 0); STG_A(As0, 128, 0); STG_A(As0, 192, 0);
  STG_B(Bs0, 0, 0); STG_B(Bs0, 64, 0); STG_B(Bs0, 128, 0); STG_B(Bs0, 192, 0);
  if (nT > 1) {
    STG_A(As1, 0, 1); STG_A(As1, 64, 1); STG_A(As1, 128, 1); STG_A(As1, 192, 1);
  }

  f32x4 acc[8][4] = {};
  for (int tt = 0; tt < nT; ++tt) {
    short* const Ac = (tt & 1) ? As1 : As0;  // tile tt's A; dest for A(tt+2)
    short* const Bc = (tt & 1) ? Bs1 : Bs0;  // tile tt's B
    short* const Bn = (tt & 1) ? Bs0 : Bs1;  // dest for B(tt+1)

    if (tt + 1 < nT) {
      VMCNT(4);  // leave A(tt+1) in flight
    } else {
      VMCNT(0);
    }
    BARRIER();

    if (tt + 1 < nT) {
      STG_B(Bn, 0, tt + 1); STG_B(Bn, 64, tt + 1);
      STG_B(Bn, 128, tt + 1); STG_B(Bn, 192, tt + 1);
    }

    short8 alo[4][2], blo[2][2], bhi[2][2];
#pragma unroll
    for (int i = 0; i < 4; ++i) {
      alo[i][0] = RD(Ac, wr + i * 16, 0);
      alo[i][1] = RD(Ac, wr + i * 16, 1);
    }
#pragma unroll
    for (int j = 0; j < 2; ++j) {
      blo[j][0] = RD(Bc, wc + j * 16, 0);
      blo[j][1] = RD(Bc, wc + j * 16, 1);
    }
#pragma unroll
    for (int i = 0; i < 4; ++i)
#pragma unroll
      for (int j = 0; j < 2; ++j) {
        MFMA16(alo[i][0], blo[j][0], acc[i][j]);
        MFMA16(alo[i][1], blo[j][1], acc[i][j]);
      }
#pragma unroll
    for (int j = 0; j < 2; ++j) {
      bhi[j][0] = RD(Bc, wc + 32 + j * 16, 0);
      bhi[j][1] = RD(Bc, wc + 32 + j * 16, 1);
    }
#pragma unroll
    for (int i = 0; i < 4; ++i)
#pragma unroll
      for (int j = 0; j < 2; ++j) {
        MFMA16(alo[i][0], bhi[j][0], acc[i][2 + j]);
        MFMA16(alo[i][1], bhi[j][1], acc[i][2 + j]);
      }

    short8 ahi[4][2];
#pragma unroll
    for (int i = 0; i < 4; ++i) {
      ahi[i][0] = RD(Ac, wr + 64 + i * 16, 0);
      ahi[i][1] = RD(Ac, wr + 64 + i * 16, 1);
    }
    LGKM0();    // my reads of Ac landed in regs
    BARRIER();  // ALL waves' reads of Ac complete -> safe to overwrite

    if (tt + 2 < nT) {
      STG_A(Ac, 0, tt + 2); STG_A(Ac, 64, tt + 2);
      STG_A(Ac, 128, tt + 2); STG_A(Ac, 192, tt + 2);
    }

#pragma unroll
    for (int i = 0; i < 4; ++i)
#pragma unroll
      for (int j = 0; j < 2; ++j) {
        MFMA16(ahi[i][0], blo[j][0], acc[4 + i][j]);
        MFMA16(ahi[i][1], blo[j][1], acc[4 + i][j]);
      }
#pragma unroll
    for (int i = 0; i < 4; ++i)
#pragma unroll
      for (int j = 0; j < 2; ++j) {
        MFMA16(ahi[i][0], bhi[j][0], acc[4 + i][2 + j]);
        MFMA16(ahi[i][1], bhi[j][1], acc[4 + i][2 + j]);
      }
  }

  float* const F = (float*)SM + wave * 4096;
#pragma unroll
  for (int h = 0; h < 2; ++h) {
    if (h) LGKM0();
#pragma unroll
    for (int i = 0; i < 4; ++i)
#pragma unroll
      for (int j = 0; j < 4; ++j)
#pragma unroll
        for (int r = 0; r < 4; ++r)
          F[(i * 16 + quad * 4 + r) * 64 + j * 16 + m16] =
              acc[h * 4 + i][j][r] * cscale;
    LGKM0();
#pragma unroll
    for (int p = 0; p < 16; ++p) {
      const int row = p * 4 + quad;
      const f32x4 vv = *(const f32x4*)(F + row * 64 + m16 * 4);
      const size_t gi =
          (size_t)(rowBase + wr + h * 64 + row) * ldc + colBase + wc + m16 * 4;
      if (outF32) {
        *(f32x4*)((float*)C + gi) = vv;
      } else {
        short4v s;
#pragma unroll
        for (int r = 0; r < 4; ++r) s[r] = f2bs(vv[r]);
        *(short4v*)((short*)C + gi) = s;
      }
    }
  }
#undef STG_A
#undef STG_B
#undef RD
}

// ----------------------------------------------------------------------------
// gemm256x128 (R7-verified): 256x128, BK=64, 8 waves (4M x 2N), v12 ledger.
// ----------------------------------------------------------------------------
__device__ __forceinline__ void gemm256x128(const short* __restrict__ A,
                                            int lda,
                                            const short* __restrict__ B,
                                            int ldb, void* __restrict__ C,
                                            int ldc, int rowBase, int colBase,
                                            int K, short* SM, int outF32) {
  const int t = threadIdx.x;
  const int wave = t >> 6;
  const int lane = t & 63;
  const int quad = lane >> 4;
  const int m16 = lane & 15;
  const int wr = (wave >> 1) * 64;  // 4 M-waves
  const int wc = (wave & 1) * 64;   // 2 N-waves

  short* const As0 = SM;            // 32 KB: 256 rows x 64
  short* const As1 = SM + 16384;
  short* const Bs0 = SM + 32768;    // 16 KB: 128 rows x 64
  short* const Bs1 = SM + 40960;

  const int sr = t >> 3;  // 0..63
  const int sc8 = ((t & 7) ^ (sr & 7)) * 8;
  const short* aS = A + (size_t)(rowBase + sr) * lda + sc8;
  const short* bS = B + (size_t)(colBase + sr) * ldb + sc8;
  const int dOff = wave * 512;

#define STG_A(buf, rg, kt) \
  async_ld16(aS + (size_t)(rg) * lda + (kt) * 64, (buf) + (rg) * 64 + dOff)
#define STG_B(buf, rg, kt) \
  async_ld16(bS + (size_t)(rg) * ldb + (kt) * 64, (buf) + (rg) * 64 + dOff)
#define RD(buf, row0, kh)                          \
  (*(const short8*)((buf) + ((row0) + m16) * 64 +  \
                    ((((kh) * 4 + quad) ^ (m16 & 7)) * 8)))

  const int nT = K >> 6;
  // prologue: A(0) 4 + B(0) 2 + A(1) 4 = 10 loads in flight.
  STG_A(As0, 0, 0); STG_A(As0, 64, 0); STG_A(As0, 128, 0); STG_A(As0, 192, 0);
  STG_B(Bs0, 0, 0); STG_B(Bs0, 64, 0);
  if (nT > 1) {
    STG_A(As1, 0, 1); STG_A(As1, 64, 1); STG_A(As1, 128, 1); STG_A(As1, 192, 1);
  }

  f32x4 acc[4][4] = {};
  for (int tt = 0; tt < nT; ++tt) {
    short* const Ac = (tt & 1) ? As1 : As0;  // tile tt's A; dest for A(tt+2)
    short* const Bc = (tt & 1) ? Bs1 : Bs0;  // tile tt's B
    short* const Bn = (tt & 1) ? Bs0 : Bs1;  // dest for B(tt+1)

    if (tt + 1 < nT) {
      VMCNT(4);  // leave A(tt+1) in flight
    } else {
      VMCNT(0);
    }
    BARRIER();

    if (tt + 1 < nT) { STG_B(Bn, 0, tt + 1); STG_B(Bn, 64, tt + 1); }

    // ---- kh=0 half ----
    short8 a0[4], b0[4];
#pragma unroll
    for (int i = 0; i < 4; ++i) a0[i] = RD(Ac, wr + i * 16, 0);
#pragma unroll
    for (int j = 0; j < 4; ++j) b0[j] = RD(Bc, wc + j * 16, 0);
#pragma unroll
    for (int i = 0; i < 4; ++i)
#pragma unroll
      for (int j = 0; j < 4; ++j) MFMA16(a0[i], b0[j], acc[i][j]);

    // ---- kh=1 reads (hidden under kh=0 MFMAs) ----
    short8 a1[4], b1[4];
#pragma unroll
    for (int i = 0; i < 4; ++i) a1[i] = RD(Ac, wr + i * 16, 1);
#pragma unroll
    for (int j = 0; j < 4; ++j) b1[j] = RD(Bc, wc + j * 16, 1);
    LGKM0();
    BARRIER();  // all waves done reading Ac/Bc

    if (tt + 2 < nT) {
      STG_A(Ac, 0, tt + 2); STG_A(Ac, 64, tt + 2);
      STG_A(Ac, 128, tt + 2); STG_A(Ac, 192, tt + 2);
    }

#pragma unroll
    for (int i = 0; i < 4; ++i)
#pragma unroll
      for (int j = 0; j < 4; ++j) MFMA16(a1[i], b1[j], acc[i][j]);
  }

  // ---- epilogue: per-wave f32 LDS transit -> coalesced 16B stores ----
  float* const F = (float*)SM + wave * 4096;  // 16 KB per wave (needs 128 KB)
#pragma unroll
  for (int i = 0; i < 4; ++i)
#pragma unroll
    for (int j = 0; j < 4; ++j)
#pragma unroll
      for (int r = 0; r < 4; ++r)
        F[(i * 16 + quad * 4 + r) * 64 + j * 16 + m16] = acc[i][j][r];
  LGKM0();
#pragma unroll
  for (int p = 0; p < 16; ++p) {
    const int row = p * 4 + quad;
    const f32x4 vv = *(const f32x4*)(F + row * 64 + m16 * 4);
    const size_t gi =
        (size_t)(rowBase + wr + row) * ldc + colBase + wc + m16 * 4;
    if (outF32) {
      *(f32x4*)((float*)C + gi) = vv;
    } else {
      short4v s;
#pragma unroll
      for (int r = 0; r < 4; ++r) s[r] = f2bs(vv[r]);
      *(short4v*)((short*)C + gi) = s;
    }
  }
#undef STG_A
#undef STG_B
#undef RD
}

// grid: 192 blocks (16 row-tiles x 12 col-tiles: Q 8, K 2, V 2), 512 threads.
// Q outputs pre-scaled by 1/sqrt(64)*log2e (folded softmax scale).
__global__ __launch_bounds__(512, 2) void qkv_gemm_kernel(
    const short* __restrict__ R, const short* __restrict__ WQ,
    const short* __restrict__ WK, const short* __restrict__ WV,
    short* __restrict__ q, short* __restrict__ k, short* __restrict__ v) {
  __shared__ __align__(16) short SM[65536];  // 128 KB
  const int lid = blockIdx.x;
  const int nl = (lid & 7) * 24 + (lid >> 3);
  const int ct = nl % 12;
  const int rt = nl / 12;
  const short* Bm;
  short* Cout;
  int colBase, ldc;
  float cs = 1.0f;
  if (ct < 8) {
    Bm = WQ; Cout = q; colBase = ct * 256; ldc = 2048;
    cs = 0.125f * 1.44269504088896340736f;
  } else if (ct < 10) {
    Bm = WK; Cout = k; colBase = (ct - 8) * 256; ldc = 512;
  } else {
    Bm = WV; Cout = v; colBase = (ct - 10) * 256; ldc = 512;
  }
  gemm256(R, 2048, Bm, 2048, Cout, ldc, rt * 256, colBase, 2048, SM, 0, cs);
}

// grid: 256 blocks (16 row-tiles x 16 col-tiles of 128), 512 threads.
__global__ __launch_bounds__(512, 2) void out_gemm_kernel(
    const short* __restrict__ A, const short* __restrict__ Bt,
    void* __restrict__ C, const short* __restrict__ sniffsrc) {
  __shared__ __align__(16) short SM[65536];  // 128 KB
  const int outF32 = block_sniff_f32(sniffsrc, (int*)SM);
  const int lid = blockIdx.x;
  const int nl = (lid & 7) * 32 + (lid >> 3);
  const int ct = nl & 15;
  const int rt = nl >> 4;
  gemm256x128(A, 2048, Bt, 2048, C, 2048, rt * 256, ct * 128, 2048, SM,
              outF32);
}

// ----------------------------------------------------------------------------
// v [2,2048,512] -> vT [2,512,2048]
// ----------------------------------------------------------------------------
__global__ __launch_bounds__(256) void vt_kernel(const short* __restrict__ v,
                                                 short* __restrict__ vt) {
  __shared__ short tile[64][65];
  const int hb = blockIdx.x * 64, pb = blockIdx.y * 64, b = blockIdx.z;
  const int tx = threadIdx.x & 63, ty = threadIdx.x >> 6;
#pragma unroll
  for (int i = 0; i < 16; ++i) {
    const int r = ty + i * 4;
    tile[r][tx] = v[((size_t)(b * 2048 + pb + r)) * 512 + hb + tx];
  }
  __syncthreads();
#pragma unroll
  for (int i = 0; i < 16; ++i) {
    const int r = ty + i * 4;
    vt[((size_t)(b * 512 + hb + r)) * 2048 + pb + tx] = tile[tx][r];
  }
}

// ----------------------------------------------------------------------------
// Causal flash attention v16 (R10-verified, 67 us): split counted waits.
//   top: vmcnt(2) waits K(t) only; barrier; issue K(t+1).
//   mid: vmcnt(2|0) waits V(t); barrier; issue V(t+1).
// Raw s_barrier everywhere -- no implicit full drain.
// ----------------------------------------------------------------------------
__global__ __launch_bounds__(256, 3) void attn_kernel(
    const short* __restrict__ qbuf, const short* __restrict__ kbuf,
    const short* __restrict__ vtb, short* __restrict__ obuf) {
  __shared__ __align__(16) short Ks[2][64 * 64];  // 16 KB K double-buffer
  __shared__ __align__(16) short Vs[2][64 * 64];  // 16 KB V^T double-buffer
  __shared__ __align__(16) short Pb[4][32 * 64];  // 16 KB per-wave P transit

  const int b = blockIdx.x >> 3;
  const int kv = blockIdx.x & 7;
  const int qc = 63 - blockIdx.y;  // long-first dispatch
  const int t = threadIdx.x;
  const int wave = t >> 6;
  const int hd = kv * 4 + wave;
  const int lane = t & 63;
  const int quad = lane >> 4;
  const int col = lane & 15;
  const int rb0 = qc * 32;

  // Q B-frags: B[k=quad*8+j (+32*kh)][n=col] = Q[qrow][h] (pre-scaled)
  short8 qf[2][2];
#pragma unroll
  for (int nt = 0; nt < 2; ++nt) {
    const int qr = rb0 + nt * 16 + col;
    const short* qp = qbuf + ((size_t)(b * 2048 + qr)) * 2048 + hd * 64 + quad * 8;
    qf[nt][0] = *(const short8*)(qp);
    qf[nt][1] = *(const short8*)(qp + 32);
  }

  // all-ones bf16 A-frag for MFMA row-sum
  short8 ones;
#pragma unroll
  for (int i = 0; i < 8; ++i) ones[i] = (short)0x3F80;

  f32x4 oacc[2][4] = {};
  f32x4 sacc[2] = {};  // row-sum accumulators (all regs identical)

  short* P = &Pb[wave][0];
  const int swz = 4 * (col & 3);  // P chunk swizzle

  const int sRow = t >> 3;
  const int sPos = t & 7;
  const int r1 = sRow + 32;
  const short* kRow0 = kbuf + ((size_t)(b * 2048 + sRow)) * 512 + kv * 64 +
                       ((sPos ^ (sRow & 7)) * 8);
  const short* kRow1 = kbuf + ((size_t)(b * 2048 + r1)) * 512 + kv * 64 +
                       ((sPos ^ (r1 & 7)) * 8);
  const short* vRow0 = vtb + ((size_t)(b * 512 + kv * 64 + sRow)) * 2048 +
                       ((sPos ^ (sRow & 7)) * 8);
  const short* vRow1 = vtb + ((size_t)(b * 512 + kv * 64 + r1)) * 2048 +
                       ((sPos ^ (r1 & 7)) * 8);

  const int nkt = (qc >> 1) + 1;  // exact causal trip count (same all waves)

  // prologue: stage K tile 0 FIRST, then V tile 0 (issue order = wait order)
  async_ld16(kRow0, &Ks[0][wave * 512]);
  async_ld16(kRow1, &Ks[0][2048 + wave * 512]);
  async_ld16(vRow0, &Vs[0][wave * 512]);
  async_ld16(vRow1, &Vs[0][2048 + wave * 512]);

  for (int kt = 0; kt < nkt; ++kt) {
    const int nb = (kt + 1) & 1;
    // ---- top: K(kt) resident; V(kt) still in flight ----
    VMCNT(2);
    BARRIER();  // all waves' K(kt) in LDS; K[nb] readers done (prev mid bar)
    if (kt + 1 < nkt) {
      const size_t ko = (size_t)(kt + 1) * 64 * 512;  // K: 64 rows ahead
      async_ld16(kRow0 + ko, &Ks[nb][wave * 512]);
      async_ld16(kRow1 + ko, &Ks[nb][2048 + wave * 512]);
    }
    const int ktb = kt * 64;
    const short* ks = &Ks[kt & 1][0];
    const short* vs = &Vs[kt & 1][0];

    // ---- K A-frags from LDS: A[m=mt*16+col][k=quad*8+j (+32kh)]
    short8 kf[4][2];
#pragma unroll
    for (int mt = 0; mt < 4; ++mt) {
      const int krow = mt * 16 + col;  // krow&7 == col&7
      kf[mt][0] = *(const short8*)(ks + krow * 64 + ((quad ^ (col & 7)) * 8));
      kf[mt][1] = *(const short8*)(ks + krow * 64 + (((4 + quad) ^ (col & 7)) * 8));
    }

#pragma unroll
    for (int nt = 0; nt < 2; ++nt) {
      const int rb = rb0 + nt * 16;

      f32x4 st[4];
#pragma unroll
      for (int mt = 0; mt < 4; ++mt) {
        f32x4 z = {0.f, 0.f, 0.f, 0.f};
        z = __builtin_amdgcn_mfma_f32_16x16x32_bf16(kf[mt][0], qf[nt][0], z, 0, 0, 0);
        z = __builtin_amdgcn_mfma_f32_16x16x32_bf16(kf[mt][1], qf[nt][1], z, 0, 0, 0);
        st[mt] = z;
      }

      if (ktb + 63 > rb) {  // diagonal overlap: per-score causal mask
        const int qrow = rb + col;
#pragma unroll
        for (int mt = 0; mt < 4; ++mt)
#pragma unroll
          for (int r = 0; r < 4; ++r)
            if (ktb + mt * 16 + quad * 4 + r > qrow) st[mt][r] = -1.0e30f;
      }

      // ---- one-pass softmax: P = exp2(S); masked -> 0; sum via MFMA later
#pragma unroll
      for (int mt = 0; mt < 4; ++mt) {
        const float p0 = exp2f(st[mt][0]);
        const float p1 = exp2f(st[mt][1]);
        const float p2 = exp2f(st[mt][2]);
        const float p3 = exp2f(st[mt][3]);
        *(short4v*)(P + (nt * 16 + col) * 64 + (quad + 4 * (mt ^ (col & 3))) * 4) =
            pk4bf16(p0, p1, p2, p3);
      }
    }

    LGKM0();  // P visible wave-wide (P is per-wave)

    // ---- mid: V(kt) resident; K(kt+1) stays in flight under PV ----
    if (kt + 1 < nkt) {
      VMCNT(2);
    } else {
      VMCNT(0);  // no K(kt+1) issued -> V(kt) is all that's outstanding
    }
    BARRIER();  // all waves' V(kt) in LDS; V[nb] readers done (prev top bar)
    if (kt + 1 < nkt) {
      const int vo = (kt + 1) * 64;  // V^T: 64 keys ahead
      async_ld16(vRow0 + vo, &Vs[nb][wave * 512]);
      async_ld16(vRow1 + vo, &Vs[nb][2048 + wave * 512]);
    }

    // P^T B-frags: B[k=key=quad*8+j (+32kh)][n=col]
    short8 pf[2][2];
#pragma unroll
    for (int nt = 0; nt < 2; ++nt) {
      const int base = (nt * 16 + col) * 64;
      pf[nt][0] = *(const short8*)(P + base + ((2 * quad) ^ swz) * 4);
      pf[nt][1] = *(const short8*)(P + base + ((8 + 2 * quad) ^ swz) * 4);
    }

    // ---- row-sum via ones-row MFMA: D[*][q] = sum_k P[k][q]
#pragma unroll
    for (int nt = 0; nt < 2; ++nt) {
      sacc[nt] = __builtin_amdgcn_mfma_f32_16x16x32_bf16(ones, pf[nt][0],
                                                         sacc[nt], 0, 0, 0);
      sacc[nt] = __builtin_amdgcn_mfma_f32_16x16x32_bf16(ones, pf[nt][1],
                                                         sacc[nt], 0, 0, 0);
    }

    // ---- V^T A-frags from LDS + PV accumulate
#pragma unroll
    for (int ct = 0; ct < 4; ++ct) {
      const int h = ct * 16 + col;  // h&7 == col&7
      const short8 va = *(const short8*)(vs + h * 64 + ((quad ^ (col & 7)) * 8));
      const short8 vb = *(const short8*)(vs + h * 64 + (((4 + quad) ^ (col & 7)) * 8));
#pragma unroll
      for (int nt = 0; nt < 2; ++nt) {
        oacc[nt][ct] = __builtin_amdgcn_mfma_f32_16x16x32_bf16(
            va, pf[nt][0], oacc[nt][ct], 0, 0, 0);
        oacc[nt][ct] = __builtin_amdgcn_mfma_f32_16x16x32_bf16(
            vb, pf[nt][1], oacc[nt][ct], 0, 0, 0);
      }
    }
  }

  // ---- epilogue: O/l -> LDS (rows qlocal x 64 h) -> line-coalesced stores
  const float inv0 = 1.0f / sacc[0][0];
  const float inv1 = 1.0f / sacc[1][0];
#pragma unroll
  for (int nt = 0; nt < 2; ++nt) {
    const float inv = nt ? inv1 : inv0;
#pragma unroll
    for (int ct = 0; ct < 4; ++ct) {
      *(short4v*)(P + (nt * 16 + col) * 64 + ct * 16 + quad * 4) =
          pk4bf16(oacc[nt][ct][0] * inv, oacc[nt][ct][1] * inv,
                  oacc[nt][ct][2] * inv, oacc[nt][ct][3] * inv);
    }
  }
  asm volatile("s_waitcnt lgkmcnt(0)" ::: "memory");
  // 8 lanes x 16B cover one 128B output row; 64 lanes -> 8 rows per pass.
#pragma unroll
  for (int p = 0; p < 4; ++p) {
    const int qlocal = (lane >> 3) + 8 * p;
    const short8 row = *(const short8*)(P + qlocal * 64 + (lane & 7) * 8);
    *(short8*)(obuf + ((size_t)(b * 2048 + rb0 + qlocal)) * 2048 + hd * 64 +
               (lane & 7) * 8) = row;
  }
}

// ----------------------------------------------------------------------------
extern "C" void kernel_launch(void* const* d_in, const int* in_sizes, int n_in,
                              void* d_out, int out_size, void* d_ws,
                              size_t ws_size, hipStream_t stream) {
  char* ws = (char*)d_ws;
  short* rbuf = (short*)(ws + 256);  // [4096,2048] bf16
  short* wqb = rbuf + 8388608;       // [2048,2048]
  short* wkb = wqb + 4194304;        // [512,2048]
  short* wvb = wkb + 1048576;        // [512,2048]
  short* kbuf = wvb + 1048576;       // [4096,512]
  short* vbuf = kbuf + 2097152;      // [4096,512]
  short* abuf = vbuf + 2097152;      // [4096,2048]
  short* wot = abuf + 8388608;       // [2048,2048]
  short* vtb = wqb;                  // [2,512,2048] aliases spent W_Q copy
  short* qbuf = (short*)d_out;       // q scratch lives in d_out

  hipLaunchKernelGGL(prep_kernel, dim3(8192), dim3(256), 0, stream,
                     d_in[0], d_in[1], d_in[2], d_in[3], rbuf, wqb, wkb, wvb,
                     d_in[4], wot);
  hipLaunchKernelGGL(qkv_gemm_kernel, dim3(192), dim3(512), 0, stream,
                     rbuf, wqb, wkb, wvb, qbuf, kbuf, vbuf);
  hipLaunchKernelGGL(vt_kernel, dim3(8, 32, 2), dim3(256), 0, stream,
                     vbuf, vtb);
  hipLaunchKernelGGL(attn_kernel, dim3(16, 64), dim3(256), 0, stream,
                     qbuf, kbuf, vtb, abuf);
  hipLaunchKernelGGL(out_gemm_kernel, dim3(256), dim3(512), 0, stream,
                     abuf, wot, (void*)d_out, (const short*)d_in[0]);
}

// Round 13
// 260.325 us; speedup vs baseline: 1.0969x; 1.0169x over previous
//
#include <hip/hip_runtime.h>

// ============================================================================
// Attention_14362370637857 on MI355X (gfx950).
// B=2, S=2048, D_MODEL=2048, NH=32, NKV=8 (GQA rep=4), DH=64.
//
// v19 = v18 (264.7 us anchor) + ONE change: attn's exp2f -> raw v_exp_f32
// (inline asm). Without fast-math, exp2f lowers to a multi-instruction libm
// sequence (~6-10 VALU each x 32/lane/tile); scores are bounded and the
// masked -1e30 underflows to 0 in HW, so bare v_exp_f32 is exact here.
// ============================================================================

typedef __attribute__((ext_vector_type(8))) short short8;   // 8 bf16
typedef __attribute__((ext_vector_type(4))) short short4v;  // 4 bf16 = 8B
typedef __attribute__((ext_vector_type(4))) float f32x4;    // MFMA 16x16 C/D

__device__ __forceinline__ short f2bs(float f) {  // f32 -> bf16 bits, RNE
  unsigned u = __float_as_uint(f);
  u = (u + 0x7fffu + ((u >> 16) & 1u)) >> 16;
  return (short)u;
}
__device__ __forceinline__ float bs2f(short s) {  // bf16 bits -> f32
  return __uint_as_float(((unsigned)(unsigned short)s) << 16);
}

__device__ __forceinline__ void async_ld16(const void* g, void* l) {
  __builtin_amdgcn_global_load_lds((__attribute__((address_space(1))) void*)(g),
                                   (__attribute__((address_space(3))) void*)(l),
                                   16, 0, 0);
}

// Raw v_exp_f32: D = 2^S0, single instruction. Bypasses libm's range/denorm
// fixup code (scores bounded; -1e30 underflows to +0 in HW).
__device__ __forceinline__ float fexp2(float x) {
  float r;
  asm("v_exp_f32 %0, %1" : "=v"(r) : "v"(x));
  return r;
}

#define BARRIER()                       \
  do {                                  \
    asm volatile("" ::: "memory");      \
    __builtin_amdgcn_s_barrier();       \
    asm volatile("" ::: "memory");      \
  } while (0)
#define LGKM0()                                          \
  do {                                                   \
    asm volatile("s_waitcnt lgkmcnt(0)" ::: "memory");   \
    __builtin_amdgcn_sched_barrier(0);                   \
  } while (0)
#define VMCNT(n) asm volatile("s_waitcnt vmcnt(" #n ")" ::: "memory")
#define MFMA16(a, b, c) \
  (c) = __builtin_amdgcn_mfma_f32_16x16x32_bf16((a), (b), (c), 0, 0, 0)

// Pack 4 f32 -> 4 bf16 (RNE) via v_cvt_pk_bf16_f32 (no builtin on gfx950).
__device__ __forceinline__ short4v pk4bf16(float p0, float p1, float p2,
                                           float p3) {
  union {
    unsigned u[2];
    short4v s;
  } pk;
  asm("v_cvt_pk_bf16_f32 %0, %1, %2" : "=v"(pk.u[0]) : "v"(p0), "v"(p1));
  asm("v_cvt_pk_bf16_f32 %0, %1, %2" : "=v"(pk.u[1]) : "v"(p2), "v"(p3));
  return pk.s;
}

// ----------------------------------------------------------------------------
// Block-uniform dtype sniff: read the first 512 shorts of residual as bf16;
// if input is really f32, mantissa-half shorts decode to huge bf16 values.
// ----------------------------------------------------------------------------
__device__ __forceinline__ int block_sniff_f32(const short* __restrict__ r,
                                               int* bad) {
  if (threadIdx.x == 0) *bad = 0;
  __syncthreads();
  int my = 0;
  for (int i = threadIdx.x; i < 512; i += blockDim.x) {
    float x = bs2f(r[i]);
    if (!(fabsf(x) < 100.0f)) my = 1;
  }
  if (my) atomicOr(bad, 1);
  __syncthreads();
  return *bad;
}

// ----------------------------------------------------------------------------
// prep: blocks [0,7168) convert residual/W_Q/W_K/W_V -> canonical bf16;
//       blocks [7168,8192) transpose W_O -> W_O^T (flag-aware read).
// ----------------------------------------------------------------------------
__global__ __launch_bounds__(256) void prep_kernel(
    const void* __restrict__ s0, const void* __restrict__ s1,
    const void* __restrict__ s2, const void* __restrict__ s3,
    short* __restrict__ d0, short* __restrict__ d1, short* __restrict__ d2,
    short* __restrict__ d3, const void* __restrict__ wo,
    short* __restrict__ wot) {
  __shared__ short tile[64][65];
  __shared__ int badsh;
  const int isf = block_sniff_f32((const short*)s0, &badsh);
  const int bid = blockIdx.x;
  if (bid < 7168) {
    long off = (long)bid * 256 + threadIdx.x;
    const void* src;
    short* dst;
    if (off < 1048576) {
      src = s0; dst = d0;
    } else if ((off -= 1048576) < 524288) {
      src = s1; dst = d1;
    } else if ((off -= 524288) < 131072) {
      src = s2; dst = d2;
    } else {
      off -= 131072; src = s3; dst = d3;
    }
    const long e = off * 8;
    short8 v;
    if (isf) {
      const float* f = (const float*)src + e;
      const f32x4 a = *(const f32x4*)(f);
      const f32x4 b = *(const f32x4*)(f + 4);
#pragma unroll
      for (int j = 0; j < 4; ++j) {
        v[j] = f2bs(a[j]);
        v[4 + j] = f2bs(b[j]);
      }
    } else {
      v = *(const short8*)((const short*)src + e);
    }
    *(short8*)(dst + e) = v;
  } else {
    const int tb = bid - 7168;
    const int bx = tb & 31, by = tb >> 5;
    const int tx = threadIdx.x & 63, ty = threadIdx.x >> 6;
#pragma unroll
    for (int i = 0; i < 16; ++i) {
      const int r = ty + i * 4;
      const size_t idx = (size_t)(by * 64 + r) * 2048 + bx * 64 + tx;
      tile[r][tx] =
          isf ? f2bs(((const float*)wo)[idx]) : ((const short*)wo)[idx];
    }
    __syncthreads();
#pragma unroll
    for (int i = 0; i < 16; ++i) {
      const int r = ty + i * 4;
      wot[(size_t)(bx * 64 + r) * 2048 + by * 64 + tx] = tile[tx][r];
    }
  }
}

// ----------------------------------------------------------------------------
// gemm256 (R7-verified): C = cscale*A*B^T, 256x256, BK=64, 8 waves (2Mx4N),
// free-flow 2-barrier tile, v12 ledger: B(t+1)@top, A(t+2)@mid, vmcnt(4).
// ----------------------------------------------------------------------------
__device__ __forceinline__ void gemm256(const short* __restrict__ A, int lda,
                                        const short* __restrict__ B, int ldb,
                                        void* __restrict__ C, int ldc,
                                        int rowBase, int colBase, int K,
                                        short* SM, int outF32, float cscale) {
  const int t = threadIdx.x;
  const int wave = t >> 6;
  const int lane = t & 63;
  const int quad = lane >> 4;
  const int m16 = lane & 15;
  const int wr = (wave >> 2) * 128;  // 2 M-waves
  const int wc = (wave & 3) * 64;    // 4 N-waves

  short* const As0 = SM;             // 32 KB each buffer: 256 rows x 64 bf16
  short* const As1 = SM + 16384;
  short* const Bs0 = SM + 32768;
  short* const Bs1 = SM + 49152;

  const int sr = t >> 3;  // 0..63
  const int sc8 = ((t & 7) ^ (sr & 7)) * 8;
  const short* aS = A + (size_t)(rowBase + sr) * lda + sc8;
  const short* bS = B + (size_t)(colBase + sr) * ldb + sc8;
  const int dOff = wave * 512;

#define STG_A(buf, rg, kt) \
  async_ld16(aS + (size_t)(rg) * lda + (kt) * 64, (buf) + (rg) * 64 + dOff)
#define STG_B(buf, rg, kt) \
  async_ld16(bS + (size_t)(rg) * ldb + (kt) * 64, (buf) + (rg) * 64 + dOff)
#define RD(buf, row0, kh)                          \
  (*(const short8*)((buf) + ((row0) + m16) * 64 +  \
                    ((((kh) * 4 + quad) ^ (m16 & 7)) * 8)))

  const int nT = K >> 6;
  STG_A(As0, 0, 0); STG_A(As0, 64, 0); STG_A(As0, 128, 0); STG_A(As0, 192, 0);
  STG_B(Bs0, 0, 0); STG_B(Bs0, 64, 0); STG_B(Bs0, 128, 0); STG_B(Bs0, 192, 0);
  if (nT > 1) {
    STG_A(As1, 0, 1); STG_A(As1, 64, 1); STG_A(As1, 128, 1); STG_A(As1, 192, 1);
  }

  f32x4 acc[8][4] = {};
  for (int tt = 0; tt < nT; ++tt) {
    short* const Ac = (tt & 1) ? As1 : As0;  // tile tt's A; dest for A(tt+2)
    short* const Bc = (tt & 1) ? Bs1 : Bs0;  // tile tt's B
    short* const Bn = (tt & 1) ? Bs0 : Bs1;  // dest for B(tt+1)

    if (tt + 1 < nT) {
      VMCNT(4);  // leave A(tt+1) in flight
    } else {
      VMCNT(0);
    }
    BARRIER();

    if (tt + 1 < nT) {
      STG_B(Bn, 0, tt + 1); STG_B(Bn, 64, tt + 1);
      STG_B(Bn, 128, tt + 1); STG_B(Bn, 192, tt + 1);
    }

    short8 alo[4][2], blo[2][2], bhi[2][2];
#pragma unroll
    for (int i = 0; i < 4; ++i) {
      alo[i][0] = RD(Ac, wr + i * 16, 0);
      alo[i][1] = RD(Ac, wr + i * 16, 1);
    }
#pragma unroll
    for (int j = 0; j < 2; ++j) {
      blo[j][0] = RD(Bc, wc + j * 16, 0);
      blo[j][1] = RD(Bc, wc + j * 16, 1);
    }
#pragma unroll
    for (int i = 0; i < 4; ++i)
#pragma unroll
      for (int j = 0; j < 2; ++j) {
        MFMA16(alo[i][0], blo[j][0], acc[i][j]);
        MFMA16(alo[i][1], blo[j][1], acc[i][j]);
      }
#pragma unroll
    for (int j = 0; j < 2; ++j) {
      bhi[j][0] = RD(Bc, wc + 32 + j * 16, 0);
      bhi[j][1] = RD(Bc, wc + 32 + j * 16, 1);
    }
#pragma unroll
    for (int i = 0; i < 4; ++i)
#pragma unroll
      for (int j = 0; j < 2; ++j) {
        MFMA16(alo[i][0], bhi[j][0], acc[i][2 + j]);
        MFMA16(alo[i][1], bhi[j][1], acc[i][2 + j]);
      }

    short8 ahi[4][2];
#pragma unroll
    for (int i = 0; i < 4; ++i) {
      ahi[i][0] = RD(Ac, wr + 64 + i * 16, 0);
      ahi[i][1] = RD(Ac, wr + 64 + i * 16, 1);
    }
    LGKM0();    // my reads of Ac landed in regs
    BARRIER();  // ALL waves' reads of Ac complete -> safe to overwrite

    if (tt + 2 < nT) {
      STG_A(Ac, 0, tt + 2); STG_A(Ac, 64, tt + 2);
      STG_A(Ac, 128, tt + 2); STG_A(Ac, 192, tt + 2);
    }

#pragma unroll
    for (int i = 0; i < 4; ++i)
#pragma unroll
      for (int j = 0; j < 2; ++j) {
        MFMA16(ahi[i][0], blo[j][0], acc[4 + i][j]);
        MFMA16(ahi[i][1], blo[j][1], acc[4 + i][j]);
      }
#pragma unroll
    for (int i = 0; i < 4; ++i)
#pragma unroll
      for (int j = 0; j < 2; ++j) {
        MFMA16(ahi[i][0], bhi[j][0], acc[4 + i][2 + j]);
        MFMA16(ahi[i][1], bhi[j][1], acc[4 + i][2 + j]);
      }
  }

  float* const F = (float*)SM + wave * 4096;
#pragma unroll
  for (int h = 0; h < 2; ++h) {
    if (h) LGKM0();
#pragma unroll
    for (int i = 0; i < 4; ++i)
#pragma unroll
      for (int j = 0; j < 4; ++j)
#pragma unroll
        for (int r = 0; r < 4; ++r)
          F[(i * 16 + quad * 4 + r) * 64 + j * 16 + m16] =
              acc[h * 4 + i][j][r] * cscale;
    LGKM0();
#pragma unroll
    for (int p = 0; p < 16; ++p) {
      const int row = p * 4 + quad;
      const f32x4 vv = *(const f32x4*)(F + row * 64 + m16 * 4);
      const size_t gi =
          (size_t)(rowBase + wr + h * 64 + row) * ldc + colBase + wc + m16 * 4;
      if (outF32) {
        *(f32x4*)((float*)C + gi) = vv;
      } else {
        short4v s;
#pragma unroll
        for (int r = 0; r < 4; ++r) s[r] = f2bs(vv[r]);
        *(short4v*)((short*)C + gi) = s;
      }
    }
  }
#undef STG_A
#undef STG_B
#undef RD
}

// ----------------------------------------------------------------------------
// gemm256x128 (R7-verified): 256x128, BK=64, 8 waves (4M x 2N), v12 ledger.
// ----------------------------------------------------------------------------
__device__ __forceinline__ void gemm256x128(const short* __restrict__ A,
                                            int lda,
                                            const short* __restrict__ B,
                                            int ldb, void* __restrict__ C,
                                            int ldc, int rowBase, int colBase,
                                            int K, short* SM, int outF32) {
  const int t = threadIdx.x;
  const int wave = t >> 6;
  const int lane = t & 63;
  const int quad = lane >> 4;
  const int m16 = lane & 15;
  const int wr = (wave >> 1) * 64;  // 4 M-waves
  const int wc = (wave & 1) * 64;   // 2 N-waves

  short* const As0 = SM;            // 32 KB: 256 rows x 64
  short* const As1 = SM + 16384;
  short* const Bs0 = SM + 32768;    // 16 KB: 128 rows x 64
  short* const Bs1 = SM + 40960;

  const int sr = t >> 3;  // 0..63
  const int sc8 = ((t & 7) ^ (sr & 7)) * 8;
  const short* aS = A + (size_t)(rowBase + sr) * lda + sc8;
  const short* bS = B + (size_t)(colBase + sr) * ldb + sc8;
  const int dOff = wave * 512;

#define STG_A(buf, rg, kt) \
  async_ld16(aS + (size_t)(rg) * lda + (kt) * 64, (buf) + (rg) * 64 + dOff)
#define STG_B(buf, rg, kt) \
  async_ld16(bS + (size_t)(rg) * ldb + (kt) * 64, (buf) + (rg) * 64 + dOff)
#define RD(buf, row0, kh)                          \
  (*(const short8*)((buf) + ((row0) + m16) * 64 +  \
                    ((((kh) * 4 + quad) ^ (m16 & 7)) * 8)))

  const int nT = K >> 6;
  // prologue: A(0) 4 + B(0) 2 + A(1) 4 = 10 loads in flight.
  STG_A(As0, 0, 0); STG_A(As0, 64, 0); STG_A(As0, 128, 0); STG_A(As0, 192, 0);
  STG_B(Bs0, 0, 0); STG_B(Bs0, 64, 0);
  if (nT > 1) {
    STG_A(As1, 0, 1); STG_A(As1, 64, 1); STG_A(As1, 128, 1); STG_A(As1, 192, 1);
  }

  f32x4 acc[4][4] = {};
  for (int tt = 0; tt < nT; ++tt) {
    short* const Ac = (tt & 1) ? As1 : As0;  // tile tt's A; dest for A(tt+2)
    short* const Bc = (tt & 1) ? Bs1 : Bs0;  // tile tt's B
    short* const Bn = (tt & 1) ? Bs0 : Bs1;  // dest for B(tt+1)

    if (tt + 1 < nT) {
      VMCNT(4);  // leave A(tt+1) in flight
    } else {
      VMCNT(0);
    }
    BARRIER();

    if (tt + 1 < nT) { STG_B(Bn, 0, tt + 1); STG_B(Bn, 64, tt + 1); }

    // ---- kh=0 half ----
    short8 a0[4], b0[4];
#pragma unroll
    for (int i = 0; i < 4; ++i) a0[i] = RD(Ac, wr + i * 16, 0);
#pragma unroll
    for (int j = 0; j < 4; ++j) b0[j] = RD(Bc, wc + j * 16, 0);
#pragma unroll
    for (int i = 0; i < 4; ++i)
#pragma unroll
      for (int j = 0; j < 4; ++j) MFMA16(a0[i], b0[j], acc[i][j]);

    // ---- kh=1 reads (hidden under kh=0 MFMAs) ----
    short8 a1[4], b1[4];
#pragma unroll
    for (int i = 0; i < 4; ++i) a1[i] = RD(Ac, wr + i * 16, 1);
#pragma unroll
    for (int j = 0; j < 4; ++j) b1[j] = RD(Bc, wc + j * 16, 1);
    LGKM0();
    BARRIER();  // all waves done reading Ac/Bc

    if (tt + 2 < nT) {
      STG_A(Ac, 0, tt + 2); STG_A(Ac, 64, tt + 2);
      STG_A(Ac, 128, tt + 2); STG_A(Ac, 192, tt + 2);
    }

#pragma unroll
    for (int i = 0; i < 4; ++i)
#pragma unroll
      for (int j = 0; j < 4; ++j) MFMA16(a1[i], b1[j], acc[i][j]);
  }

  // ---- epilogue: per-wave f32 LDS transit -> coalesced 16B stores ----
  float* const F = (float*)SM + wave * 4096;  // 16 KB per wave (needs 128 KB)
#pragma unroll
  for (int i = 0; i < 4; ++i)
#pragma unroll
    for (int j = 0; j < 4; ++j)
#pragma unroll
      for (int r = 0; r < 4; ++r)
        F[(i * 16 + quad * 4 + r) * 64 + j * 16 + m16] = acc[i][j][r];
  LGKM0();
#pragma unroll
  for (int p = 0; p < 16; ++p) {
    const int row = p * 4 + quad;
    const f32x4 vv = *(const f32x4*)(F + row * 64 + m16 * 4);
    const size_t gi =
        (size_t)(rowBase + wr + row) * ldc + colBase + wc + m16 * 4;
    if (outF32) {
      *(f32x4*)((float*)C + gi) = vv;
    } else {
      short4v s;
#pragma unroll
      for (int r = 0; r < 4; ++r) s[r] = f2bs(vv[r]);
      *(short4v*)((short*)C + gi) = s;
    }
  }
#undef STG_A
#undef STG_B
#undef RD
}

// grid: 192 blocks (16 row-tiles x 12 col-tiles: Q 8, K 2, V 2), 512 threads.
// Q outputs pre-scaled by 1/sqrt(64)*log2e (folded softmax scale).
__global__ __launch_bounds__(512, 2) void qkv_gemm_kernel(
    const short* __restrict__ R, const short* __restrict__ WQ,
    const short* __restrict__ WK, const short* __restrict__ WV,
    short* __restrict__ q, short* __restrict__ k, short* __restrict__ v) {
  __shared__ __align__(16) short SM[65536];  // 128 KB
  const int lid = blockIdx.x;
  const int nl = (lid & 7) * 24 + (lid >> 3);
  const int ct = nl % 12;
  const int rt = nl / 12;
  const short* Bm;
  short* Cout;
  int colBase, ldc;
  float cs = 1.0f;
  if (ct < 8) {
    Bm = WQ; Cout = q; colBase = ct * 256; ldc = 2048;
    cs = 0.125f * 1.44269504088896340736f;
  } else if (ct < 10) {
    Bm = WK; Cout = k; colBase = (ct - 8) * 256; ldc = 512;
  } else {
    Bm = WV; Cout = v; colBase = (ct - 10) * 256; ldc = 512;
  }
  gemm256(R, 2048, Bm, 2048, Cout, ldc, rt * 256, colBase, 2048, SM, 0, cs);
}

// grid: 256 blocks (16 row-tiles x 16 col-tiles of 128), 512 threads.
__global__ __launch_bounds__(512, 2) void out_gemm_kernel(
    const short* __restrict__ A, const short* __restrict__ Bt,
    void* __restrict__ C, const short* __restrict__ sniffsrc) {
  __shared__ __align__(16) short SM[65536];  // 128 KB
  const int outF32 = block_sniff_f32(sniffsrc, (int*)SM);
  const int lid = blockIdx.x;
  const int nl = (lid & 7) * 32 + (lid >> 3);
  const int ct = nl & 15;
  const int rt = nl >> 4;
  gemm256x128(A, 2048, Bt, 2048, C, 2048, rt * 256, ct * 128, 2048, SM,
              outF32);
}

// ----------------------------------------------------------------------------
// v [2,2048,512] -> vT [2,512,2048]
// ----------------------------------------------------------------------------
__global__ __launch_bounds__(256) void vt_kernel(const short* __restrict__ v,
                                                 short* __restrict__ vt) {
  __shared__ short tile[64][65];
  const int hb = blockIdx.x * 64, pb = blockIdx.y * 64, b = blockIdx.z;
  const int tx = threadIdx.x & 63, ty = threadIdx.x >> 6;
#pragma unroll
  for (int i = 0; i < 16; ++i) {
    const int r = ty + i * 4;
    tile[r][tx] = v[((size_t)(b * 2048 + pb + r)) * 512 + hb + tx];
  }
  __syncthreads();
#pragma unroll
  for (int i = 0; i < 16; ++i) {
    const int r = ty + i * 4;
    vt[((size_t)(b * 512 + hb + r)) * 2048 + pb + tx] = tile[tx][r];
  }
}

// ----------------------------------------------------------------------------
// Causal flash attention v19: v16 split counted waits + raw v_exp_f32.
//   top: vmcnt(2) waits K(t) only; barrier; issue K(t+1).
//   mid: vmcnt(2|0) waits V(t); barrier; issue V(t+1).
// Raw s_barrier everywhere -- no implicit full drain.
// ----------------------------------------------------------------------------
__global__ __launch_bounds__(256, 3) void attn_kernel(
    const short* __restrict__ qbuf, const short* __restrict__ kbuf,
    const short* __restrict__ vtb, short* __restrict__ obuf) {
  __shared__ __align__(16) short Ks[2][64 * 64];  // 16 KB K double-buffer
  __shared__ __align__(16) short Vs[2][64 * 64];  // 16 KB V^T double-buffer
  __shared__ __align__(16) short Pb[4][32 * 64];  // 16 KB per-wave P transit

  const int b = blockIdx.x >> 3;
  const int kv = blockIdx.x & 7;
  const int qc = 63 - blockIdx.y;  // long-first dispatch
  const int t = threadIdx.x;
  const int wave = t >> 6;
  const int hd = kv * 4 + wave;
  const int lane = t & 63;
  const int quad = lane >> 4;
  const int col = lane & 15;
  const int rb0 = qc * 32;

  // Q B-frags: B[k=quad*8+j (+32*kh)][n=col] = Q[qrow][h] (pre-scaled)
  short8 qf[2][2];
#pragma unroll
  for (int nt = 0; nt < 2; ++nt) {
    const int qr = rb0 + nt * 16 + col;
    const short* qp = qbuf + ((size_t)(b * 2048 + qr)) * 2048 + hd * 64 + quad * 8;
    qf[nt][0] = *(const short8*)(qp);
    qf[nt][1] = *(const short8*)(qp + 32);
  }

  // all-ones bf16 A-frag for MFMA row-sum
  short8 ones;
#pragma unroll
  for (int i = 0; i < 8; ++i) ones[i] = (short)0x3F80;

  f32x4 oacc[2][4] = {};
  f32x4 sacc[2] = {};  // row-sum accumulators (all regs identical)

  short* P = &Pb[wave][0];
  const int swz = 4 * (col & 3);  // P chunk swizzle

  const int sRow = t >> 3;
  const int sPos = t & 7;
  const int r1 = sRow + 32;
  const short* kRow0 = kbuf + ((size_t)(b * 2048 + sRow)) * 512 + kv * 64 +
                       ((sPos ^ (sRow & 7)) * 8);
  const short* kRow1 = kbuf + ((size_t)(b * 2048 + r1)) * 512 + kv * 64 +
                       ((sPos ^ (r1 & 7)) * 8);
  const short* vRow0 = vtb + ((size_t)(b * 512 + kv * 64 + sRow)) * 2048 +
                       ((sPos ^ (sRow & 7)) * 8);
  const short* vRow1 = vtb + ((size_t)(b * 512 + kv * 64 + r1)) * 2048 +
                       ((sPos ^ (r1 & 7)) * 8);

  const int nkt = (qc >> 1) + 1;  // exact causal trip count (same all waves)

  // prologue: stage K tile 0 FIRST, then V tile 0 (issue order = wait order)
  async_ld16(kRow0, &Ks[0][wave * 512]);
  async_ld16(kRow1, &Ks[0][2048 + wave * 512]);
  async_ld16(vRow0, &Vs[0][wave * 512]);
  async_ld16(vRow1, &Vs[0][2048 + wave * 512]);

  for (int kt = 0; kt < nkt; ++kt) {
    const int nb = (kt + 1) & 1;
    // ---- top: K(kt) resident; V(kt) still in flight ----
    VMCNT(2);
    BARRIER();  // all waves' K(kt) in LDS; K[nb] readers done (prev mid bar)
    if (kt + 1 < nkt) {
      const size_t ko = (size_t)(kt + 1) * 64 * 512;  // K: 64 rows ahead
      async_ld16(kRow0 + ko, &Ks[nb][wave * 512]);
      async_ld16(kRow1 + ko, &Ks[nb][2048 + wave * 512]);
    }
    const int ktb = kt * 64;
    const short* ks = &Ks[kt & 1][0];
    const short* vs = &Vs[kt & 1][0];

    // ---- K A-frags from LDS: A[m=mt*16+col][k=quad*8+j (+32kh)]
    short8 kf[4][2];
#pragma unroll
    for (int mt = 0; mt < 4; ++mt) {
      const int krow = mt * 16 + col;  // krow&7 == col&7
      kf[mt][0] = *(const short8*)(ks + krow * 64 + ((quad ^ (col & 7)) * 8));
      kf[mt][1] = *(const short8*)(ks + krow * 64 + (((4 + quad) ^ (col & 7)) * 8));
    }

#pragma unroll
    for (int nt = 0; nt < 2; ++nt) {
      const int rb = rb0 + nt * 16;

      f32x4 st[4];
#pragma unroll
      for (int mt = 0; mt < 4; ++mt) {
        f32x4 z = {0.f, 0.f, 0.f, 0.f};
        z = __builtin_amdgcn_mfma_f32_16x16x32_bf16(kf[mt][0], qf[nt][0], z, 0, 0, 0);
        z = __builtin_amdgcn_mfma_f32_16x16x32_bf16(kf[mt][1], qf[nt][1], z, 0, 0, 0);
        st[mt] = z;
      }

      if (ktb + 63 > rb) {  // diagonal overlap: per-score causal mask
        const int qrow = rb + col;
#pragma unroll
        for (int mt = 0; mt < 4; ++mt)
#pragma unroll
          for (int r = 0; r < 4; ++r)
            if (ktb + mt * 16 + quad * 4 + r > qrow) st[mt][r] = -1.0e30f;
      }

      // ---- one-pass softmax: P = 2^S via raw v_exp_f32; masked -> 0
#pragma unroll
      for (int mt = 0; mt < 4; ++mt) {
        const float p0 = fexp2(st[mt][0]);
        const float p1 = fexp2(st[mt][1]);
        const float p2 = fexp2(st[mt][2]);
        const float p3 = fexp2(st[mt][3]);
        *(short4v*)(P + (nt * 16 + col) * 64 + (quad + 4 * (mt ^ (col & 3))) * 4) =
            pk4bf16(p0, p1, p2, p3);
      }
    }

    LGKM0();  // P visible wave-wide (P is per-wave)

    // ---- mid: V(kt) resident; K(kt+1) stays in flight under PV ----
    if (kt + 1 < nkt) {
      VMCNT(2);
    } else {
      VMCNT(0);  // no K(kt+1) issued -> V(kt) is all that's outstanding
    }
    BARRIER();  // all waves' V(kt) in LDS; V[nb] readers done (prev top bar)
    if (kt + 1 < nkt) {
      const int vo = (kt + 1) * 64;  // V^T: 64 keys ahead
      async_ld16(vRow0 + vo, &Vs[nb][wave * 512]);
      async_ld16(vRow1 + vo, &Vs[nb][2048 + wave * 512]);
    }

    // P^T B-frags: B[k=key=quad*8+j (+32kh)][n=col]
    short8 pf[2][2];
#pragma unroll
    for (int nt = 0; nt < 2; ++nt) {
      const int base = (nt * 16 + col) * 64;
      pf[nt][0] = *(const short8*)(P + base + ((2 * quad) ^ swz) * 4);
      pf[nt][1] = *(const short8*)(P + base + ((8 + 2 * quad) ^ swz) * 4);
    }

    // ---- row-sum via ones-row MFMA: D[*][q] = sum_k P[k][q]
#pragma unroll
    for (int nt = 0; nt < 2; ++nt) {
      sacc[nt] = __builtin_amdgcn_mfma_f32_16x16x32_bf16(ones, pf[nt][0],
                                                         sacc[nt], 0, 0, 0);
      sacc[nt] = __builtin_amdgcn_mfma_f32_16x16x32_bf16(ones, pf[nt][1],
                                                         sacc[nt], 0, 0, 0);
    }

    // ---- V^T A-frags from LDS + PV accumulate
#pragma unroll
    for (int ct = 0; ct < 4; ++ct) {
      const int h = ct * 16 + col;  // h&7 == col&7
      const short8 va = *(const short8*)(vs + h * 64 + ((quad ^ (col & 7)) * 8));
      const short8 vb = *(const short8*)(vs + h * 64 + (((4 + quad) ^ (col & 7)) * 8));
#pragma unroll
      for (int nt = 0; nt < 2; ++nt) {
        oacc[nt][ct] = __builtin_amdgcn_mfma_f32_16x16x32_bf16(
            va, pf[nt][0], oacc[nt][ct], 0, 0, 0);
        oacc[nt][ct] = __builtin_amdgcn_mfma_f32_16x16x32_bf16(
            vb, pf[nt][1], oacc[nt][ct], 0, 0, 0);
      }
    }
  }

  // ---- epilogue: O/l -> LDS (rows qlocal x 64 h) -> line-coalesced stores
  const float inv0 = 1.0f / sacc[0][0];
  const float inv1 = 1.0f / sacc[1][0];
#pragma unroll
  for (int nt = 0; nt < 2; ++nt) {
    const float inv = nt ? inv1 : inv0;
#pragma unroll
    for (int ct = 0; ct < 4; ++ct) {
      *(short4v*)(P + (nt * 16 + col) * 64 + ct * 16 + quad * 4) =
          pk4bf16(oacc[nt][ct][0] * inv, oacc[nt][ct][1] * inv,
                  oacc[nt][ct][2] * inv, oacc[nt][ct][3] * inv);
    }
  }
  asm volatile("s_waitcnt lgkmcnt(0)" ::: "memory");
  // 8 lanes x 16B cover one 128B output row; 64 lanes -> 8 rows per pass.
#pragma unroll
  for (int p = 0; p < 4; ++p) {
    const int qlocal = (lane >> 3) + 8 * p;
    const short8 row = *(const short8*)(P + qlocal * 64 + (lane & 7) * 8);
    *(short8*)(obuf + ((size_t)(b * 2048 + rb0 + qlocal)) * 2048 + hd * 64 +
               (lane & 7) * 8) = row;
  }
}

// ----------------------------------------------------------------------------
extern "C" void kernel_launch(void* const* d_in, const int* in_sizes, int n_in,
                              void* d_out, int out_size, void* d_ws,
                              size_t ws_size, hipStream_t stream) {
  char* ws = (char*)d_ws;
  short* rbuf = (short*)(ws + 256);  // [4096,2048] bf16
  short* wqb = rbuf + 8388608;       // [2048,2048]
  short* wkb = wqb + 4194304;        // [512,2048]
  short* wvb = wkb + 1048576;        // [512,2048]
  short* kbuf = wvb + 1048576;       // [4096,512]
  short* vbuf = kbuf + 2097152;      // [4096,512]
  short* abuf = vbuf + 2097152;      // [4096,2048]
  short* wot = abuf + 8388608;       // [2048,2048]
  short* vtb = wqb;                  // [2,512,2048] aliases spent W_Q copy
  short* qbuf = (short*)d_out;       // q scratch lives in d_out

  hipLaunchKernelGGL(prep_kernel, dim3(8192), dim3(256), 0, stream,
                     d_in[0], d_in[1], d_in[2], d_in[3], rbuf, wqb, wkb, wvb,
                     d_in[4], wot);
  hipLaunchKernelGGL(qkv_gemm_kernel, dim3(192), dim3(512), 0, stream,
                     rbuf, wqb, wkb, wvb, qbuf, kbuf, vbuf);
  hipLaunchKernelGGL(vt_kernel, dim3(8, 32, 2), dim3(256), 0, stream,
                     vbuf, vtb);
  hipLaunchKernelGGL(attn_kernel, dim3(16, 64), dim3(256), 0, stream,
                     qbuf, kbuf, vtb, abuf);
  hipLaunchKernelGGL(out_gemm_kernel, dim3(256), dim3(512), 0, stream,
                     abuf, wot, (void*)d_out, (const short*)d_in[0]);
}